// Round 1
// baseline (366.227 us; speedup 1.0000x reference)
//
#include <hip/hip_runtime.h>
#include <hip/hip_bf16.h>

// Problem constants
constexpr int B_   = 8;
constexpr int D_   = 1024;
constexpr int T_   = 512;
constexpr int HID_ = 256;
constexpr int NH_  = 4;
constexpr int NL_  = 2;
constexpr float ALPHA_ = 0.2f;
constexpr float EPS_   = 1e-5f;
constexpr int OUT_ = 64;
constexpr int M_ = B_ * D_;      // 8192 rows
constexpr int DT_ = D_ * T_;     // 524288
constexpr int KIN_ = 2 * T_;     // 1024
constexpr int CKS_ = 132;        // checkpoint row stride in floats: [0,128)=P1/P2 pairs, [128,130)=scalars

typedef __attribute__((ext_vector_type(8))) short short8;   // 8 bf16 (4 VGPRs)
typedef __attribute__((ext_vector_type(4))) float floatx4;  // 4 fp32 acc

__device__ __forceinline__ unsigned short f2bf(float f) {
    unsigned int u = __float_as_uint(f);
    unsigned int r = u + 0x7fffu + ((u >> 16) & 1u);   // round-to-nearest-even
    return (unsigned short)(r >> 16);
}
__device__ __forceinline__ float bf2f(unsigned short u) {
    return __uint_as_float(((unsigned int)u) << 16);
}
// monotone float<->uint key for atomicMax on signed floats
__device__ __forceinline__ unsigned int kenc(float f) {
    unsigned int u = __float_as_uint(f);
    return (u & 0x80000000u) ? ~u : (u | 0x80000000u);
}
__device__ __forceinline__ float kdec(unsigned int k) {
    unsigned int u = (k & 0x80000000u) ? (k ^ 0x80000000u) : ~k;
    return __uint_as_float(u);
}

// ---------------------------------------------------------------------------
// 1) Fused prep: blocks [0,512): imputation -> Ain bf16 [M][1024]=[X_mean|mask]
//    blocks [512,2560): weight transpose/convert + rmaxkey init
// ---------------------------------------------------------------------------
__global__ __launch_bounds__(256) void prep_k(const float* __restrict__ X,
                                              const float* __restrict__ Mk,
                                              const float* __restrict__ W_in,
                                              const float* __restrict__ gatW,
                                              const float* __restrict__ W_out,
                                              unsigned short* __restrict__ Ain,
                                              unsigned short* __restrict__ Wt_in,
                                              unsigned short* __restrict__ Wcat,
                                              unsigned short* __restrict__ WtO,
                                              unsigned int* __restrict__ rmaxkey) {
    int bx = blockIdx.x;
    if (bx < 512) {
        int idx4 = (bx * 256 + threadIdx.x) * 4;   // over D*T
        int t = idx4 & (T_ - 1);
        int d = idx4 >> 9;
        float4 x[B_], m[B_];
        float4 s = {0, 0, 0, 0}, c = {0, 0, 0, 0};
#pragma unroll
        for (int b = 0; b < B_; b++) {
            x[b] = *(const float4*)&X[(size_t)b * DT_ + idx4];
            m[b] = *(const float4*)&Mk[(size_t)b * DT_ + idx4];
            s.x += x[b].x * m[b].x; s.y += x[b].y * m[b].y;
            s.z += x[b].z * m[b].z; s.w += x[b].w * m[b].w;
            c.x += m[b].x; c.y += m[b].y; c.z += m[b].z; c.w += m[b].w;
        }
        float4 pm;
        pm.x = s.x / (c.x + 1e-10f); pm.y = s.y / (c.y + 1e-10f);
        pm.z = s.z / (c.z + 1e-10f); pm.w = s.w / (c.w + 1e-10f);
#pragma unroll
        for (int b = 0; b < B_; b++) {
            size_t row = (size_t)b * D_ + d;
            ushort4 xm, mk;
            xm.x = f2bf(x[b].x * m[b].x + (1.f - m[b].x) * pm.x);
            xm.y = f2bf(x[b].y * m[b].y + (1.f - m[b].y) * pm.y);
            xm.z = f2bf(x[b].z * m[b].z + (1.f - m[b].z) * pm.z);
            xm.w = f2bf(x[b].w * m[b].w + (1.f - m[b].w) * pm.w);
            mk.x = f2bf(m[b].x); mk.y = f2bf(m[b].y);
            mk.z = f2bf(m[b].z); mk.w = f2bf(m[b].w);
            *(ushort4*)&Ain[row * KIN_ + t]      = xm;
            *(ushort4*)&Ain[row * KIN_ + T_ + t] = mk;
        }
    } else {
        int idx = (bx - 512) * 256 + threadIdx.x;
        if (idx < 64) rmaxkey[idx] = 0u;
        if (idx < 262144) {
            int n = idx >> 10, k = idx & 1023;     // Wt_in[n][k] = W_in[k][n]
            Wt_in[idx] = f2bf(W_in[(size_t)k * HID_ + n]);
        } else if (idx < 393216) {
            int j = idx - 262144;
            int l = j >> 16, n = (j >> 8) & 255, k = j & 255;
            int h = n >> 6, e = n & 63;
            Wcat[j] = f2bf(gatW[(((size_t)(l * NH_ + h) * HID_) + k) * OUT_ + e]);
        } else {
            int j = idx - 393216;
            int n = j >> 8, k = j & 255;           // WtO[n][k] = W_out[k][n]
            WtO[j] = f2bf(W_out[(size_t)k * T_ + n]);
        }
    }
}

// ---------------------------------------------------------------------------
// 2) bf16 MFMA GEMM. BM=64 BN=64 BK=64, 4 waves, wave = 16 rows x 64 cols.
//    Padded LDS (stride 72) kills bank conflicts; reg-staged ping-pong.
//    MODE 0: fp32 C (+bias). MODE 1: + bf16 copy.
//    MODE 2: hW row-major [bh][m][e] bf16 + fused s_l/s_r/rmax.
// ---------------------------------------------------------------------------
template <int MODE>
__global__ __launch_bounds__(256) void gemm_bf16_k(
        const unsigned short* __restrict__ A,    // M x K bf16
        const unsigned short* __restrict__ Bt,   // N x K bf16 (B transposed)
        const float* __restrict__ bias,          // N or null (MODE 0/1)
        float* __restrict__ C,                   // M x N fp32 (MODE 0/1)
        unsigned short* __restrict__ Cb,         // bf16 copy (MODE1) / hwN (MODE2)
        const float* __restrict__ ga,            // gat_a + l*512 (MODE2)
        float* __restrict__ s_l,                 // (MODE2)
        float* __restrict__ s_r,                 // (MODE2)
        unsigned int* __restrict__ rmaxkey,      // + l*32 (MODE2)
        int Nsz, int Ksz) {
    __shared__ __align__(16) unsigned short As[2][64 * 72];  // 18 KB, padded
    __shared__ __align__(16) unsigned short Bs[2][64 * 72];  // 18 KB
    int tid = threadIdx.x;
    int wave = tid >> 6, lane = tid & 63;
    int q = lane >> 4, r16 = lane & 15;
    int rowbase = blockIdx.y * 64;
    int colbase = blockIdx.x * 64;

    int srow = tid >> 3, sk = (tid & 7) * 8;         // staging slot
    const unsigned short* Ap0 = A + (size_t)(rowbase + srow) * Ksz + sk;
    const unsigned short* Ap1 = A + (size_t)(rowbase + srow + 32) * Ksz + sk;
    const unsigned short* Bp0 = Bt + (size_t)(colbase + srow) * Ksz + sk;
    const unsigned short* Bp1 = Bt + (size_t)(colbase + srow + 32) * Ksz + sk;
    int la0 = srow * 72 + sk, la1 = (srow + 32) * 72 + sk;

    floatx4 acc[4];
#pragma unroll
    for (int i = 0; i < 4; i++) acc[i] = (floatx4)0.f;

    uint4 pa0 = *(const uint4*)Ap0, pa1 = *(const uint4*)Ap1;
    uint4 pb0 = *(const uint4*)Bp0, pb1 = *(const uint4*)Bp1;
    *(uint4*)&As[0][la0] = pa0;
    *(uint4*)&As[0][la1] = pa1;
    *(uint4*)&Bs[0][la0] = pb0;
    *(uint4*)&Bs[0][la1] = pb1;

    int nk = Ksz >> 6;
    for (int it = 0; it < nk; it++) {
        int cur = it & 1;
        __syncthreads();
        if (it + 1 < nk) {
            int kt = (it + 1) << 6;
            pa0 = *(const uint4*)(Ap0 + kt);
            pa1 = *(const uint4*)(Ap1 + kt);
            pb0 = *(const uint4*)(Bp0 + kt);
            pb1 = *(const uint4*)(Bp1 + kt);
        }
#pragma unroll
        for (int t = 0; t < 2; t++) {
            short8 a = *(const short8*)&As[cur][(wave * 16 + r16) * 72 + t * 32 + q * 8];
#pragma unroll
            for (int ni = 0; ni < 4; ni++) {
                short8 b = *(const short8*)&Bs[cur][(ni * 16 + r16) * 72 + t * 32 + q * 8];
                acc[ni] = __builtin_amdgcn_mfma_f32_16x16x32_bf16(a, b, acc[ni], 0, 0, 0);
            }
        }
        if (it + 1 < nk) {
            int nxt = cur ^ 1;
            *(uint4*)&As[nxt][la0] = pa0;
            *(uint4*)&As[nxt][la1] = pa1;
            *(uint4*)&Bs[nxt][la0] = pb0;
            *(uint4*)&Bs[nxt][la1] = pb1;
        }
    }
    // ---- epilogue. C/D map: col=lane&15, row=(lane>>4)*4+reg ----
    if constexpr (MODE == 2) {
        int bhh = ((rowbase >> 10) << 2) + blockIdx.x;   // b*4 + h
        int nb = (rowbase & (D_ - 1)) + wave * 16;
        // hwN[bh][m][e] bf16 (row-major per head: prefix kernel reads 128B rows)
#pragma unroll
        for (int ni = 0; ni < 4; ni++) {
            int e = ni * 16 + r16;
#pragma unroll
            for (int rr = 0; rr < 4; rr++) {
                int m = nb + q * 4 + rr;
                Cb[((size_t)bhh << 16) + ((size_t)m << 6) + e] = f2bf(acc[ni][rr]);
            }
        }
        // fused s_l/s_r from fp32 acc
        const float* gab = ga + blockIdx.x * 2 * OUT_;
        float al4[4], ar4[4];
#pragma unroll
        for (int ni = 0; ni < 4; ni++) {
            al4[ni] = gab[ni * 16 + r16];
            ar4[ni] = gab[OUT_ + ni * 16 + r16];
        }
        float slv[4], srv[4];
#pragma unroll
        for (int rr = 0; rr < 4; rr++) {
            float s1 = 0.f, s2 = 0.f;
#pragma unroll
            for (int ni = 0; ni < 4; ni++) {
                s1 += acc[ni][rr] * al4[ni];
                s2 += acc[ni][rr] * ar4[ni];
            }
            slv[rr] = s1;
            srv[rr] = s2;
        }
#pragma unroll
        for (int off = 1; off < 16; off <<= 1) {
#pragma unroll
            for (int rr = 0; rr < 4; rr++) {
                slv[rr] += __shfl_xor(slv[rr], off, 64);
                srv[rr] += __shfl_xor(srv[rr], off, 64);
            }
        }
        {
            int rsel = r16 & 3;
            float sv = (rsel == 0) ? slv[0] : (rsel == 1) ? slv[1] : (rsel == 2) ? slv[2] : slv[3];
            float rv = (rsel == 0) ? srv[0] : (rsel == 1) ? srv[1] : (rsel == 2) ? srv[2] : srv[3];
            int n = nb + q * 4 + rsel;
            if (r16 < 4)                 s_l[bhh * D_ + n] = sv;
            else if (r16 >= 8 && r16 < 12) s_r[bhh * D_ + n] = rv;
        }
        float mx = fmaxf(fmaxf(srv[0], srv[1]), fmaxf(srv[2], srv[3]));
        mx = fmaxf(mx, __shfl_xor(mx, 16, 64));
        mx = fmaxf(mx, __shfl_xor(mx, 32, 64));
        if (lane == 0) atomicMax(&rmaxkey[bhh], kenc(mx));
    } else {
#pragma unroll
        for (int rr = 0; rr < 4; rr++) {
            int row = rowbase + wave * 16 + q * 4 + rr;
#pragma unroll
            for (int ni = 0; ni < 4; ni++) {
                int col = colbase + ni * 16 + r16;
                float v = acc[ni][rr] + (bias ? bias[col] : 0.f);
                C[(size_t)row * Nsz + col] = v;
                if constexpr (MODE == 1) Cb[(size_t)row * Nsz + col] = f2bf(v);
            }
        }
    }
}

// ---------------------------------------------------------------------------
// 3) Sort-factorized attention, stage A. leaky_relu(sl[n]+sr[m]) is 2-piece
//    linear in the rank-1 score => softmax factorizes exactly at the column
//    split sr[m] >= -sl[n]. Per bh: bitonic-sort sr (1024), weights
//    w1=exp(sr-rm), w2=exp(alpha*(sr-rm)), then EXCLUSIVE prefix sums of
//    w*V[sigma(t)][e] checkpointed every 4 ranks (+ scalar prefixes).
//    ck[bh][t4][2e..2e+1] = (P1,P2), [128..129] = scalar (p1s,p2s);
//    ck[bh][256][*] = totals. S1(t) = TOT - P(t)  (exact 0 at t=1024).
// ---------------------------------------------------------------------------
__global__ __launch_bounds__(512) void sortprefix_k(
        const unsigned short* __restrict__ hwN,   // [32][1024][64] bf16
        const float* __restrict__ sr_g,           // [32][1024]
        const unsigned int* __restrict__ rmaxkey, // +l*32
        float* __restrict__ srt,                  // [32][1024] sorted sr
        int* __restrict__ sig,                    // [32][1024] orig index
        float* __restrict__ wm,                   // [32][1024][2] (w1,w2)
        float* __restrict__ ck) {                 // [32][257][CKS_]
    __shared__ float skey[1024];
    __shared__ int   sidx[1024];
    __shared__ float w1s[1024], w2s[1024];
    __shared__ float csum[8][64][2];
    __shared__ float csca[8][2];
    int bh = blockIdx.x, tid = threadIdx.x;
    for (int t = tid; t < 1024; t += 512) { skey[t] = sr_g[bh * D_ + t]; sidx[t] = t; }
    __syncthreads();
    // bitonic sort ascending (pairs disjoint per pass; 2 elems/thread)
    for (int k = 2; k <= 1024; k <<= 1) {
        for (int j = k >> 1; j > 0; j >>= 1) {
            for (int t = tid; t < 1024; t += 512) {
                int ixj = t ^ j;
                if (ixj > t) {
                    bool up = ((t & k) == 0);
                    float a = skey[t], b = skey[ixj];
                    bool sw = up ? (a > b) : (a < b);
                    if (sw) {
                        skey[t] = b; skey[ixj] = a;
                        int ti = sidx[t]; sidx[t] = sidx[ixj]; sidx[ixj] = ti;
                    }
                }
            }
            __syncthreads();
        }
    }
    float rm = kdec(rmaxkey[bh]);
    for (int t = tid; t < 1024; t += 512) {
        float u = skey[t] - rm;                 // <= 0
        float w1 = __expf(u), w2 = __expf(ALPHA_ * u);
        w1s[t] = w1; w2s[t] = w2;
        srt[bh * D_ + t] = skey[t];
        sig[bh * D_ + t] = sidx[t];
        *(float2*)&wm[(size_t)(bh * D_ + t) * 2] = float2{w1, w2};
    }
    __syncthreads();
    // chunked prefix: 8 chunks of 128 ranks, 64 e-lanes each
    int e = tid & 63, c = tid >> 6;
    const unsigned short* vb = hwN + ((size_t)bh << 16);
    int t0 = c * 128;
    float a1 = 0.f, a2 = 0.f, q1 = 0.f, q2 = 0.f;
    for (int t = t0; t < t0 + 128; ++t) {
        float v = bf2f(vb[((size_t)sidx[t] << 6) + e]);   // 128B coalesced row
        a1 = fmaf(w1s[t], v, a1);
        a2 = fmaf(w2s[t], v, a2);
    }
    csum[c][e][0] = a1; csum[c][e][1] = a2;
    if (e == 0) {
        for (int t = t0; t < t0 + 128; ++t) { q1 += w1s[t]; q2 += w2s[t]; }
        csca[c][0] = q1; csca[c][1] = q2;
    }
    __syncthreads();
    float r1 = 0.f, r2 = 0.f, p1 = 0.f, p2 = 0.f;
    for (int cc = 0; cc < c; ++cc) { r1 += csum[cc][e][0]; r2 += csum[cc][e][1]; }
    if (e == 0) {
        for (int cc = 0; cc < c; ++cc) { p1 += csca[cc][0]; p2 += csca[cc][1]; }
    }
    float* ckb = ck + (size_t)bh * 257 * CKS_;
    for (int t = t0; t < t0 + 128; ++t) {
        if ((t & 3) == 0) {
            *(float2*)&ckb[(size_t)(t >> 2) * CKS_ + 2 * e] = float2{r1, r2};
            if (e == 0) *(float2*)&ckb[(size_t)(t >> 2) * CKS_ + 128] = float2{p1, p2};
        }
        float v = bf2f(vb[((size_t)sidx[t] << 6) + e]);
        r1 = fmaf(w1s[t], v, r1);
        r2 = fmaf(w2s[t], v, r2);
        if (e == 0) { p1 += w1s[t]; p2 += w2s[t]; }
    }
    if (c == 7) {   // totals at checkpoint 256 (same fp chain => S1(1024)==0 exact)
        *(float2*)&ckb[(size_t)256 * CKS_ + 2 * e] = float2{r1, r2};
        if (e == 0) *(float2*)&ckb[(size_t)256 * CKS_ + 128] = float2{p1, p2};
    }
}

// ---------------------------------------------------------------------------
// 4) Stage B: per row n & head h: binary search t = lower_bound(srt, -sl),
//    gather checkpoint + <=3 fixups, head_out = (A*(TOT-P1)+B*P2)/den,
//    then fused residual + LayerNorm (replaces addln_k; no pacc/pden).
//    Block = 32 rows x 4 heads (128 thr), grid 256.
// ---------------------------------------------------------------------------
__global__ __launch_bounds__(128) void rowln_k(
        float* __restrict__ h,                    // hbuf fp32 [M][256], in/out
        const float* __restrict__ sl_g,           // [32][1024]
        const unsigned int* __restrict__ rmaxkey, // +l*32
        const float* __restrict__ srt,
        const int* __restrict__ sig,
        const float* __restrict__ wm,
        const float* __restrict__ ck,
        const unsigned short* __restrict__ hwN,
        const float* __restrict__ g,
        const float* __restrict__ bb,
        unsigned short* __restrict__ hbf) {
    __shared__ float srtL[4][1024];   // 16 KB
    __shared__ float hnew[32][260];   // 33.3 KB (stride 260: 16B-aligned rows)
    int blk = blockIdx.x;
    int b = blk >> 5;
    int d0 = (blk & 31) << 5;
    int tid = threadIdx.x;
    for (int i = tid; i < 4096; i += 128)
        srtL[i >> 10][i & 1023] = srt[(size_t)((b * 4 + (i >> 10)) * D_) + (i & 1023)];
    __syncthreads();
    int r = tid & 31, h4 = tid >> 5;
    int bh = b * 4 + h4;
    int d = d0 + r;
    float sl = sl_g[bh * D_ + d];
    float rm = kdec(rmaxkey[bh]);
    float x = sl + rm;
    float Mn = fmaxf(x, ALPHA_ * x);               // = max_m e[n,m]
    float A  = __expf(x - Mn);
    float B2 = __expf(ALPHA_ * x - Mn);
    // t = first rank with srt[rank] >= -sl  (same predicate as leaky_relu branch)
    float key = -sl;
    int lo = 0, hi = 1024;
    while (lo < hi) {
        int mid = (lo + hi) >> 1;
        if (srtL[h4][mid] < key) lo = mid + 1; else hi = mid;
    }
    int t = lo;
    int c4 = t >> 2, nf = t & 3;
    const float* ckb = ck + ((size_t)bh * 257 + c4) * CKS_;
    const float* ckT = ck + ((size_t)bh * 257 + 256) * CKS_;
    float2 qs = *(const float2*)&ckb[128];
    float2 qT = *(const float2*)&ckT[128];
    float w1f[3], w2f[3];
    const unsigned short* vp[3];
#pragma unroll
    for (int f = 0; f < 3; ++f) {
        w1f[f] = 0.f; w2f[f] = 0.f; vp[f] = hwN;
        if (f < nf) {
            int rk = c4 * 4 + f;
            float2 ww = *(const float2*)&wm[(size_t)(bh * D_ + rk) * 2];
            w1f[f] = ww.x; w2f[f] = ww.y;
            vp[f] = hwN + ((size_t)bh << 16) + ((size_t)sig[bh * D_ + rk] << 6);
            qs.x += ww.x; qs.y += ww.y;
        }
    }
    float den = A * (qT.x - qs.x) + B2 * qs.y;     // >= exp(0) = 1
    float inv = 1.f / den;
    for (int e = 0; e < 64; ++e) {
        float2 p  = *(const float2*)&ckb[2 * e];
        float2 Tt = *(const float2*)&ckT[2 * e];
#pragma unroll
        for (int f = 0; f < 3; ++f) {
            if (f < nf) {
                float v = bf2f(vp[f][e]);
                p.x = fmaf(w1f[f], v, p.x);
                p.y = fmaf(w2f[f], v, p.y);
            }
        }
        hnew[r][h4 * 64 + e] = (A * (Tt.x - p.x) + B2 * p.y) * inv;
    }
    __syncthreads();
    // fused residual + LayerNorm: 2 waves x 16 rows each
    int wv = tid >> 6, ln = tid & 63;
    for (int rr = wv * 16; rr < wv * 16 + 16; ++rr) {
        size_t grow = ((((size_t)b << 10) + d0 + rr) << 8);   // *HID_
        float4 a  = *(const float4*)&h[grow + ln * 4];
        float4 nv = *(const float4*)&hnew[rr][ln * 4];
        float4 v = {a.x + nv.x, a.y + nv.y, a.z + nv.z, a.w + nv.w};
        float s = v.x + v.y + v.z + v.w;
#pragma unroll
        for (int off = 1; off < 64; off <<= 1) s += __shfl_xor(s, off, 64);
        float mu = s * (1.f / HID_);
        float4 dd = {v.x - mu, v.y - mu, v.z - mu, v.w - mu};
        float s2 = dd.x * dd.x + dd.y * dd.y + dd.z * dd.z + dd.w * dd.w;
#pragma unroll
        for (int off = 1; off < 64; off <<= 1) s2 += __shfl_xor(s2, off, 64);
        float rs = rsqrtf(s2 * (1.f / HID_) + EPS_);
        float4 gg = *(const float4*)&g[ln * 4];
        float4 bv = *(const float4*)&bb[ln * 4];
        float4 res;
        res.x = dd.x * rs * gg.x + bv.x;
        res.y = dd.y * rs * gg.y + bv.y;
        res.z = dd.z * rs * gg.z + bv.z;
        res.w = dd.w * rs * gg.w + bv.w;
        *(float4*)&h[grow + ln * 4] = res;
        ushort4 pk = {f2bf(res.x), f2bf(res.y), f2bf(res.z), f2bf(res.w)};
        *(ushort4*)&hbf[grow + ln * 4] = pk;
    }
}

// ---------------------------------------------------------------------------
extern "C" void kernel_launch(void* const* d_in, const int* in_sizes, int n_in,
                              void* d_out, int out_size, void* d_ws, size_t ws_size,
                              hipStream_t stream) {
    const float* X_obs = (const float*)d_in[0];
    const float* mask  = (const float*)d_in[1];
    const float* W_in  = (const float*)d_in[2];
    const float* b_in  = (const float*)d_in[3];
    const float* gat_W = (const float*)d_in[4];
    const float* gat_a = (const float*)d_in[5];
    const float* ln_g  = (const float*)d_in[6];
    const float* ln_b  = (const float*)d_in[7];
    const float* W_out = (const float*)d_in[8];
    const float* b_out = (const float*)d_in[9];
    float* out = (float*)d_out;

    // Workspace layout:
    //  [0,16M):  Ain bf16 (M x 1024), dead after gemm1; then hwN bf16
    //            [32][1024][64] at [0,4M), ck at [5M,~9.2M), wm at [10M,+256K),
    //            srt at [11M,+128K), sig at [12M,+128K)
    //  [21M,29M): hbuf fp32 (M x 256)
    //  [29M,33M): hbf bf16 (M x 256)
    //  [33M,+):   Wt_in, Wcat, WtO (bf16), slb/srb (fp32), rmaxkey (uint[64])
    char* base = (char*)d_ws;
    unsigned short* Ain = (unsigned short*)base;
    unsigned short* hwN = (unsigned short*)base;
    float* ck   = (float*)(base + (5u << 20));
    float* wm   = (float*)(base + (10u << 20));
    float* srtb = (float*)(base + (11u << 20));
    int*   sig  = (int*)(base + (12u << 20));
    float* hbuf = (float*)(base + (21u << 20));
    unsigned short* hbf   = (unsigned short*)(base + (29u << 20));
    unsigned short* Wt_in = (unsigned short*)(base + (33u << 20));
    unsigned short* Wcat  = Wt_in + (size_t)HID_ * KIN_;        // 256*1024
    unsigned short* WtO   = Wcat + (size_t)NL_ * HID_ * HID_;   // 2*256*256
    float* slb = (float*)(WtO + (size_t)T_ * HID_);             // 32*1024
    float* srb = slb + B_ * NH_ * D_;
    unsigned int* rmaxkey = (unsigned int*)(srb + B_ * NH_ * D_);  // [2][32]

    prep_k<<<2560, 256, 0, stream>>>(X_obs, mask, W_in, gat_W, W_out,
                                     Ain, Wt_in, Wcat, WtO, rmaxkey);

    // h = [X_mean|mask] @ W_in + b_in   (8192x1024)@(1024x256), fp32+bf16 out
    gemm_bf16_k<1><<<dim3(HID_ / 64, M_ / 64), 256, 0, stream>>>(
        Ain, Wt_in, b_in, hbuf, hbf, nullptr, nullptr, nullptr, nullptr,
        HID_, KIN_);

    for (int l = 0; l < NL_; l++) {
        // hW = h @ Wcat[l] -> hwN [bh][m][e] bf16 + fused s_l/s_r/rmax
        gemm_bf16_k<2><<<dim3(HID_ / 64, M_ / 64), 256, 0, stream>>>(
            hbf, Wcat + (size_t)l * HID_ * HID_, nullptr, nullptr, hwN,
            gat_a + (size_t)l * NH_ * 2 * OUT_, slb, srb, rmaxkey + l * 32,
            HID_, HID_);
        // sort sr + weighted prefix sums (replaces O(D^2) attention)
        sortprefix_k<<<32, 512, 0, stream>>>(hwN, srb, rmaxkey + l * 32,
                                             srtb, sig, wm, ck);
        // per-row gather + residual + LayerNorm (replaces attn_k + addln_k)
        rowln_k<<<256, 128, 0, stream>>>(hbuf, slb, rmaxkey + l * 32,
                                         srtb, sig, wm, ck, hwN,
                                         ln_g + (size_t)l * HID_,
                                         ln_b + (size_t)l * HID_, hbf);
    }

    // out = h @ W_out + b_out  (8192x256)@(256x512), fp32 out
    gemm_bf16_k<0><<<dim3(T_ / 64, M_ / 64), 256, 0, stream>>>(
        hbf, WtO, b_out, out, nullptr, nullptr, nullptr, nullptr, nullptr,
        T_, HID_);
}

// Round 2
// 263.616 us; speedup vs baseline: 1.3892x; 1.3892x over previous
//
#include <hip/hip_runtime.h>
#include <hip/hip_bf16.h>

// Problem constants
constexpr int B_   = 8;
constexpr int D_   = 1024;
constexpr int T_   = 512;
constexpr int HID_ = 256;
constexpr int NH_  = 4;
constexpr int NL_  = 2;
constexpr float ALPHA_ = 0.2f;
constexpr float EPS_   = 1e-5f;
constexpr int OUT_ = 64;
constexpr int M_ = B_ * D_;      // 8192 rows
constexpr int DT_ = D_ * T_;     // 524288
constexpr int KIN_ = 2 * T_;     // 1024
constexpr int CKS_ = 132;        // checkpoint row stride (floats): [0,128)=P1/P2 pairs, [128,130)=scalars

typedef __attribute__((ext_vector_type(8))) short short8;   // 8 bf16 (4 VGPRs)
typedef __attribute__((ext_vector_type(4))) float floatx4;  // 4 fp32 acc

__device__ __forceinline__ unsigned short f2bf(float f) {
    unsigned int u = __float_as_uint(f);
    unsigned int r = u + 0x7fffu + ((u >> 16) & 1u);   // round-to-nearest-even
    return (unsigned short)(r >> 16);
}
__device__ __forceinline__ float bf2f(unsigned short u) {
    return __uint_as_float(((unsigned int)u) << 16);
}
// monotone float<->uint key for atomicMax on signed floats
__device__ __forceinline__ unsigned int kenc(float f) {
    unsigned int u = __float_as_uint(f);
    return (u & 0x80000000u) ? ~u : (u | 0x80000000u);
}
__device__ __forceinline__ float kdec(unsigned int k) {
    unsigned int u = (k & 0x80000000u) ? (k ^ 0x80000000u) : ~k;
    return __uint_as_float(u);
}

// ---------------------------------------------------------------------------
// 1) Fused prep: blocks [0,512): imputation -> Ain bf16 [M][1024]=[X_mean|mask]
//    blocks [512,2560): weight transpose/convert + rmaxkey init
// ---------------------------------------------------------------------------
__global__ __launch_bounds__(256) void prep_k(const float* __restrict__ X,
                                              const float* __restrict__ Mk,
                                              const float* __restrict__ W_in,
                                              const float* __restrict__ gatW,
                                              const float* __restrict__ W_out,
                                              unsigned short* __restrict__ Ain,
                                              unsigned short* __restrict__ Wt_in,
                                              unsigned short* __restrict__ Wcat,
                                              unsigned short* __restrict__ WtO,
                                              unsigned int* __restrict__ rmaxkey) {
    int bx = blockIdx.x;
    if (bx < 512) {
        int idx4 = (bx * 256 + threadIdx.x) * 4;   // over D*T
        int t = idx4 & (T_ - 1);
        int d = idx4 >> 9;
        float4 x[B_], m[B_];
        float4 s = {0, 0, 0, 0}, c = {0, 0, 0, 0};
#pragma unroll
        for (int b = 0; b < B_; b++) {
            x[b] = *(const float4*)&X[(size_t)b * DT_ + idx4];
            m[b] = *(const float4*)&Mk[(size_t)b * DT_ + idx4];
            s.x += x[b].x * m[b].x; s.y += x[b].y * m[b].y;
            s.z += x[b].z * m[b].z; s.w += x[b].w * m[b].w;
            c.x += m[b].x; c.y += m[b].y; c.z += m[b].z; c.w += m[b].w;
        }
        float4 pm;
        pm.x = s.x / (c.x + 1e-10f); pm.y = s.y / (c.y + 1e-10f);
        pm.z = s.z / (c.z + 1e-10f); pm.w = s.w / (c.w + 1e-10f);
#pragma unroll
        for (int b = 0; b < B_; b++) {
            size_t row = (size_t)b * D_ + d;
            ushort4 xm, mk;
            xm.x = f2bf(x[b].x * m[b].x + (1.f - m[b].x) * pm.x);
            xm.y = f2bf(x[b].y * m[b].y + (1.f - m[b].y) * pm.y);
            xm.z = f2bf(x[b].z * m[b].z + (1.f - m[b].z) * pm.z);
            xm.w = f2bf(x[b].w * m[b].w + (1.f - m[b].w) * pm.w);
            mk.x = f2bf(m[b].x); mk.y = f2bf(m[b].y);
            mk.z = f2bf(m[b].z); mk.w = f2bf(m[b].w);
            *(ushort4*)&Ain[row * KIN_ + t]      = xm;
            *(ushort4*)&Ain[row * KIN_ + T_ + t] = mk;
        }
    } else {
        int idx = (bx - 512) * 256 + threadIdx.x;
        if (idx < 64) rmaxkey[idx] = 0u;
        if (idx < 262144) {
            int n = idx >> 10, k = idx & 1023;     // Wt_in[n][k] = W_in[k][n]
            Wt_in[idx] = f2bf(W_in[(size_t)k * HID_ + n]);
        } else if (idx < 393216) {
            int j = idx - 262144;
            int l = j >> 16, n = (j >> 8) & 255, k = j & 255;
            int h = n >> 6, e = n & 63;
            Wcat[j] = f2bf(gatW[(((size_t)(l * NH_ + h) * HID_) + k) * OUT_ + e]);
        } else {
            int j = idx - 393216;
            int n = j >> 8, k = j & 255;           // WtO[n][k] = W_out[k][n]
            WtO[j] = f2bf(W_out[(size_t)k * T_ + n]);
        }
    }
}

// ---------------------------------------------------------------------------
// 2) bf16 MFMA GEMM. BM=64 BN=64 BK=64, 4 waves, wave = 16 rows x 64 cols.
//    MODE 0: fp32 C (+bias). MODE 1: + bf16 copy.
//    MODE 2: hW row-major [bh][m][e] bf16 + fused s_l/s_r/rmax.
// ---------------------------------------------------------------------------
template <int MODE>
__global__ __launch_bounds__(256) void gemm_bf16_k(
        const unsigned short* __restrict__ A,    // M x K bf16
        const unsigned short* __restrict__ Bt,   // N x K bf16 (B transposed)
        const float* __restrict__ bias,          // N or null (MODE 0/1)
        float* __restrict__ C,                   // M x N fp32 (MODE 0/1)
        unsigned short* __restrict__ Cb,         // bf16 copy (MODE1) / hwN (MODE2)
        const float* __restrict__ ga,            // gat_a + l*512 (MODE2)
        float* __restrict__ s_l,                 // (MODE2)
        float* __restrict__ s_r,                 // (MODE2)
        unsigned int* __restrict__ rmaxkey,      // + l*32 (MODE2)
        int Nsz, int Ksz) {
    __shared__ __align__(16) unsigned short As[2][64 * 72];  // 18 KB, padded
    __shared__ __align__(16) unsigned short Bs[2][64 * 72];  // 18 KB
    int tid = threadIdx.x;
    int wave = tid >> 6, lane = tid & 63;
    int q = lane >> 4, r16 = lane & 15;
    int rowbase = blockIdx.y * 64;
    int colbase = blockIdx.x * 64;

    int srow = tid >> 3, sk = (tid & 7) * 8;         // staging slot
    const unsigned short* Ap0 = A + (size_t)(rowbase + srow) * Ksz + sk;
    const unsigned short* Ap1 = A + (size_t)(rowbase + srow + 32) * Ksz + sk;
    const unsigned short* Bp0 = Bt + (size_t)(colbase + srow) * Ksz + sk;
    const unsigned short* Bp1 = Bt + (size_t)(colbase + srow + 32) * Ksz + sk;
    int la0 = srow * 72 + sk, la1 = (srow + 32) * 72 + sk;

    floatx4 acc[4];
#pragma unroll
    for (int i = 0; i < 4; i++) acc[i] = (floatx4)0.f;

    uint4 pa0 = *(const uint4*)Ap0, pa1 = *(const uint4*)Ap1;
    uint4 pb0 = *(const uint4*)Bp0, pb1 = *(const uint4*)Bp1;
    *(uint4*)&As[0][la0] = pa0;
    *(uint4*)&As[0][la1] = pa1;
    *(uint4*)&Bs[0][la0] = pb0;
    *(uint4*)&Bs[0][la1] = pb1;

    int nk = Ksz >> 6;
    for (int it = 0; it < nk; it++) {
        int cur = it & 1;
        __syncthreads();
        if (it + 1 < nk) {
            int kt = (it + 1) << 6;
            pa0 = *(const uint4*)(Ap0 + kt);
            pa1 = *(const uint4*)(Ap1 + kt);
            pb0 = *(const uint4*)(Bp0 + kt);
            pb1 = *(const uint4*)(Bp1 + kt);
        }
#pragma unroll
        for (int t = 0; t < 2; t++) {
            short8 a = *(const short8*)&As[cur][(wave * 16 + r16) * 72 + t * 32 + q * 8];
#pragma unroll
            for (int ni = 0; ni < 4; ni++) {
                short8 b = *(const short8*)&Bs[cur][(ni * 16 + r16) * 72 + t * 32 + q * 8];
                acc[ni] = __builtin_amdgcn_mfma_f32_16x16x32_bf16(a, b, acc[ni], 0, 0, 0);
            }
        }
        if (it + 1 < nk) {
            int nxt = cur ^ 1;
            *(uint4*)&As[nxt][la0] = pa0;
            *(uint4*)&As[nxt][la1] = pa1;
            *(uint4*)&Bs[nxt][la0] = pb0;
            *(uint4*)&Bs[nxt][la1] = pb1;
        }
    }
    // ---- epilogue. C/D map: col=lane&15, row=(lane>>4)*4+reg ----
    if constexpr (MODE == 2) {
        int bhh = ((rowbase >> 10) << 2) + blockIdx.x;   // b*4 + h
        int nb = (rowbase & (D_ - 1)) + wave * 16;
        // hwN[bh][m][e] bf16 (row-major per head)
#pragma unroll
        for (int ni = 0; ni < 4; ni++) {
            int e = ni * 16 + r16;
#pragma unroll
            for (int rr = 0; rr < 4; rr++) {
                int m = nb + q * 4 + rr;
                Cb[((size_t)bhh << 16) + ((size_t)m << 6) + e] = f2bf(acc[ni][rr]);
            }
        }
        // fused s_l/s_r from fp32 acc
        const float* gab = ga + blockIdx.x * 2 * OUT_;
        float al4[4], ar4[4];
#pragma unroll
        for (int ni = 0; ni < 4; ni++) {
            al4[ni] = gab[ni * 16 + r16];
            ar4[ni] = gab[OUT_ + ni * 16 + r16];
        }
        float slv[4], srv[4];
#pragma unroll
        for (int rr = 0; rr < 4; rr++) {
            float s1 = 0.f, s2 = 0.f;
#pragma unroll
            for (int ni = 0; ni < 4; ni++) {
                s1 += acc[ni][rr] * al4[ni];
                s2 += acc[ni][rr] * ar4[ni];
            }
            slv[rr] = s1;
            srv[rr] = s2;
        }
#pragma unroll
        for (int off = 1; off < 16; off <<= 1) {
#pragma unroll
            for (int rr = 0; rr < 4; rr++) {
                slv[rr] += __shfl_xor(slv[rr], off, 64);
                srv[rr] += __shfl_xor(srv[rr], off, 64);
            }
        }
        {
            int rsel = r16 & 3;
            float sv = (rsel == 0) ? slv[0] : (rsel == 1) ? slv[1] : (rsel == 2) ? slv[2] : slv[3];
            float rv = (rsel == 0) ? srv[0] : (rsel == 1) ? srv[1] : (rsel == 2) ? srv[2] : srv[3];
            int n = nb + q * 4 + rsel;
            if (r16 < 4)                 s_l[bhh * D_ + n] = sv;
            else if (r16 >= 8 && r16 < 12) s_r[bhh * D_ + n] = rv;
        }
        float mx = fmaxf(fmaxf(srv[0], srv[1]), fmaxf(srv[2], srv[3]));
        mx = fmaxf(mx, __shfl_xor(mx, 16, 64));
        mx = fmaxf(mx, __shfl_xor(mx, 32, 64));
        if (lane == 0) atomicMax(&rmaxkey[bhh], kenc(mx));
    } else {
#pragma unroll
        for (int rr = 0; rr < 4; rr++) {
            int row = rowbase + wave * 16 + q * 4 + rr;
#pragma unroll
            for (int ni = 0; ni < 4; ni++) {
                int col = colbase + ni * 16 + r16;
                float v = acc[ni][rr] + (bias ? bias[col] : 0.f);
                C[(size_t)row * Nsz + col] = v;
                if constexpr (MODE == 1) Cb[(size_t)row * Nsz + col] = f2bf(v);
            }
        }
    }
}

// ---------------------------------------------------------------------------
// 3a) rank_k: exact ranking of sr per bh via counting (no sort network).
//     grid (32 bh, 16 segs of 64 elements), 1024 threads.
//     wave = m-chunk (broadcast LDS reads), lane = element in segment.
//     Writes srt (sorted keys), sig (orig idx), wm (w1,w2) at rank position.
// ---------------------------------------------------------------------------
__global__ __launch_bounds__(1024) void rank_k(
        const float* __restrict__ sr_g,
        const unsigned int* __restrict__ rmaxkey,
        float* __restrict__ srt,
        int* __restrict__ sig,
        float* __restrict__ wm) {
    __shared__ float skey[1024];
    __shared__ short part[16][64];
    int bh = blockIdx.x, seg = blockIdx.y;
    int tid = threadIdx.x;
    skey[tid] = sr_g[bh * D_ + tid];
    __syncthreads();
    int lane = tid & 63, wv = tid >> 6;
    int el = seg * 64 + lane;
    float k = skey[el];
    int m0 = wv * 64;
    int cnt = 0;
#pragma unroll 4
    for (int m = m0; m < m0 + 64; ++m) {
        float km = skey[m];                       // broadcast
        cnt += (km < k) || (km == k && m < el);   // strict total order
    }
    part[wv][lane] = (short)cnt;
    __syncthreads();
    if (tid < 64) {
        int rank = 0;
#pragma unroll
        for (int w = 0; w < 16; ++w) rank += part[w][tid];
        int elg = seg * 64 + tid;
        float key = skey[elg];
        float rm = kdec(rmaxkey[bh]);
        float u = key - rm;                       // <= 0
        float w1 = __expf(u), w2 = __expf(ALPHA_ * u);
        srt[bh * D_ + rank] = key;
        sig[bh * D_ + rank] = elg;
        *(float2*)&wm[(size_t)(bh * D_ + rank) * 2] = float2{w1, w2};
    }
}

// ---------------------------------------------------------------------------
// 3b) prefix_k: EXCLUSIVE prefix sums of w*V over sorted rank, checkpointed
//     every 4 ranks (+ scalar prefixes). 32 blocks x 1024 thr = 16 chunks
//     (wave) x 64 e-lanes, 64 ranks per chunk. ck[bh][t4][2e..2e+1]=(P1,P2),
//     [128..129]=(p1s,p2s); ck[bh][256][*]=totals (same fp chain => exact
//     endpoints at t=0 and t=1024).
// ---------------------------------------------------------------------------
__global__ __launch_bounds__(1024) void prefix_k(
        const unsigned short* __restrict__ hwN,   // [32][1024][64] bf16
        const int* __restrict__ sig,
        const float* __restrict__ wm,
        float* __restrict__ ck) {                 // [32][257][CKS_]
    __shared__ int   sidx[1024];
    __shared__ float w1s[1024], w2s[1024];
    __shared__ float csum[16][64][2];
    __shared__ float csca[16][2];
    int bh = blockIdx.x, tid = threadIdx.x;
    sidx[tid] = sig[bh * D_ + tid];
    float2 ww = *(const float2*)&wm[(size_t)(bh * D_ + tid) * 2];
    w1s[tid] = ww.x; w2s[tid] = ww.y;
    __syncthreads();
    int e = tid & 63, c = tid >> 6;               // wave = chunk
    const unsigned short* vb = hwN + ((size_t)bh << 16);
    int t0 = c * 64;
    float a1 = 0.f, a2 = 0.f;
    for (int t = t0; t < t0 + 64; ++t) {
        float v = bf2f(vb[((size_t)sidx[t] << 6) + e]);   // 128B coalesced row
        a1 = fmaf(w1s[t], v, a1);
        a2 = fmaf(w2s[t], v, a2);
    }
    csum[c][e][0] = a1; csum[c][e][1] = a2;
    if (e == 0) {
        float q1 = 0.f, q2 = 0.f;
        for (int t = t0; t < t0 + 64; ++t) { q1 += w1s[t]; q2 += w2s[t]; }
        csca[c][0] = q1; csca[c][1] = q2;
    }
    __syncthreads();
    float r1 = 0.f, r2 = 0.f, p1 = 0.f, p2 = 0.f;
    for (int cc = 0; cc < c; ++cc) { r1 += csum[cc][e][0]; r2 += csum[cc][e][1]; }
    if (e == 0)
        for (int cc = 0; cc < c; ++cc) { p1 += csca[cc][0]; p2 += csca[cc][1]; }
    float* ckb = ck + (size_t)bh * 257 * CKS_;
    for (int t = t0; t < t0 + 64; ++t) {
        if ((t & 3) == 0) {
            *(float2*)&ckb[(size_t)(t >> 2) * CKS_ + 2 * e] = float2{r1, r2};
            if (e == 0) *(float2*)&ckb[(size_t)(t >> 2) * CKS_ + 128] = float2{p1, p2};
        }
        float v = bf2f(vb[((size_t)sidx[t] << 6) + e]);
        r1 = fmaf(w1s[t], v, r1);
        r2 = fmaf(w2s[t], v, r2);
        if (e == 0) { p1 += w1s[t]; p2 += w2s[t]; }
    }
    if (c == 15) {   // totals at checkpoint 256
        *(float2*)&ckb[(size_t)256 * CKS_ + 2 * e] = float2{r1, r2};
        if (e == 0) *(float2*)&ckb[(size_t)256 * CKS_ + 128] = float2{p1, p2};
    }
}

// ---------------------------------------------------------------------------
// 4) rowln_k: per (row,head): bsearch + checkpoint gather + <=3 fixups,
//    head_out = fA*(TOT1-P1) + fB*P2 + sum cf*V, then fused residual+LN.
//    Block = 32 rows x 4 heads, 512 threads. Phase 1 is wave-per-pair with
//    lane = e (coalesced 512B ck rows). grid 256.
// ---------------------------------------------------------------------------
__global__ __launch_bounds__(512) void rowln_k(
        float* __restrict__ h,                    // hbuf fp32 [M][256], in/out
        const float* __restrict__ sl_g,           // [32][1024]
        const unsigned int* __restrict__ rmaxkey, // +l*32
        const float* __restrict__ srt,
        const int* __restrict__ sig,
        const float* __restrict__ wm,
        const float* __restrict__ ck,
        const unsigned short* __restrict__ hwN,
        const float* __restrict__ g,
        const float* __restrict__ bb,
        unsigned short* __restrict__ hbf) {
    __shared__ float srtL[4][1024];   // 16 KB
    __shared__ float hnew[32][260];   // 33.3 KB
    __shared__ float ckT1[4][64];     // branch-1 vector totals (P1 of cp 256)
    __shared__ float qTs[4][2];
    __shared__ float pdF[128][5];     // fA, fB, cf0, cf1, cf2
    __shared__ int   pdI[128][5];     // vo0, vo1, vo2, c4, nf
    int blk = blockIdx.x;
    int b = blk >> 5;
    int d0 = (blk & 31) << 5;
    int tid = threadIdx.x;
    // phase 0a: stage sorted keys + totals
    for (int i = tid; i < 4096; i += 512)
        srtL[i >> 10][i & 1023] = srt[(size_t)((b * 4 + (i >> 10)) * D_) + (i & 1023)];
    if (tid < 256) {
        int hh = tid >> 6, e = tid & 63;
        ckT1[hh][e] = ck[((size_t)(b * 4 + hh) * 257 + 256) * CKS_ + 2 * e];
    }
    if (tid < 8) {
        int hh = tid >> 1;
        qTs[hh][tid & 1] = ck[((size_t)(b * 4 + hh) * 257 + 256) * CKS_ + 128 + (tid & 1)];
    }
    __syncthreads();
    // phase 0b: 128 parallel per-pair scalar setups (one per (row,head))
    if (tid < 128) {
        int r = tid & 31, h4 = tid >> 5;
        int bh = b * 4 + h4;
        float sl = sl_g[bh * D_ + d0 + r];
        float rm = kdec(rmaxkey[bh]);
        float x = sl + rm;
        float Mn = fmaxf(x, ALPHA_ * x);          // = max_m e[n,m]
        float A  = __expf(x - Mn);
        float B2 = __expf(ALPHA_ * x - Mn);
        float key = -sl;
        int lo = 0, hi = 1024;
        while (lo < hi) {
            int mid = (lo + hi) >> 1;
            if (srtL[h4][mid] < key) lo = mid + 1; else hi = mid;
        }
        int t = lo, c4 = t >> 2, nf = t & 3;
        float2 qs = *(const float2*)&ck[((size_t)bh * 257 + c4) * CKS_ + 128];
        float w1f[3] = {0.f, 0.f, 0.f}, w2f[3] = {0.f, 0.f, 0.f};
        int vo[3] = {0, 0, 0};
#pragma unroll
        for (int f = 0; f < 3; ++f) {
            if (f < nf) {
                int rk = c4 * 4 + f;
                float2 ww = *(const float2*)&wm[(size_t)(bh * D_ + rk) * 2];
                w1f[f] = ww.x; w2f[f] = ww.y;
                vo[f] = sig[bh * D_ + rk] << 6;
                qs.x += ww.x; qs.y += ww.y;
            }
        }
        float den = A * (qTs[h4][0] - qs.x) + B2 * qs.y;
        float inv = 1.f / den;
        float fA = A * inv, fB = B2 * inv;
        pdF[tid][0] = fA; pdF[tid][1] = fB;
#pragma unroll
        for (int f = 0; f < 3; ++f) pdF[tid][2 + f] = fB * w2f[f] - fA * w1f[f];
        pdI[tid][0] = vo[0]; pdI[tid][1] = vo[1]; pdI[tid][2] = vo[2];
        pdI[tid][3] = c4;    pdI[tid][4] = nf;
    }
    __syncthreads();
    // phase 1: wave-per-pair, lane = e. 16 independent pairs per wave.
    int wv = tid >> 6, e = tid & 63;
    for (int p = wv; p < 128; p += 8) {
        int r = p & 31, h4 = p >> 5;
        int bh = b * 4 + h4;
        float fA = pdF[p][0], fB = pdF[p][1];
        int c4 = pdI[p][3], nf = pdI[p][4];
        float2 P = *(const float2*)&ck[((size_t)bh * 257 + c4) * CKS_ + 2 * e];
        float o = fA * (ckT1[h4][e] - P.x) + fB * P.y;
        const unsigned short* vb = hwN + ((size_t)bh << 16);
        if (nf > 0) o += pdF[p][2] * bf2f(vb[pdI[p][0] + e]);
        if (nf > 1) o += pdF[p][3] * bf2f(vb[pdI[p][1] + e]);
        if (nf > 2) o += pdF[p][4] * bf2f(vb[pdI[p][2] + e]);
        hnew[r][h4 * 64 + e] = o;
    }
    __syncthreads();
    // phase 2: fused residual + LayerNorm, 8 waves x 4 rows
    for (int rr = wv * 4; rr < wv * 4 + 4; ++rr) {
        size_t grow = ((((size_t)b << 10) + d0 + rr) << 8);   // *HID_
        float4 a  = *(const float4*)&h[grow + e * 4];
        float4 nv = *(const float4*)&hnew[rr][e * 4];
        float4 v = {a.x + nv.x, a.y + nv.y, a.z + nv.z, a.w + nv.w};
        float s = v.x + v.y + v.z + v.w;
#pragma unroll
        for (int off = 1; off < 64; off <<= 1) s += __shfl_xor(s, off, 64);
        float mu = s * (1.f / HID_);
        float4 dd = {v.x - mu, v.y - mu, v.z - mu, v.w - mu};
        float s2 = dd.x * dd.x + dd.y * dd.y + dd.z * dd.z + dd.w * dd.w;
#pragma unroll
        for (int off = 1; off < 64; off <<= 1) s2 += __shfl_xor(s2, off, 64);
        float rs = rsqrtf(s2 * (1.f / HID_) + EPS_);
        float4 gg = *(const float4*)&g[e * 4];
        float4 bv = *(const float4*)&bb[e * 4];
        float4 res;
        res.x = dd.x * rs * gg.x + bv.x;
        res.y = dd.y * rs * gg.y + bv.y;
        res.z = dd.z * rs * gg.z + bv.z;
        res.w = dd.w * rs * gg.w + bv.w;
        *(float4*)&h[grow + e * 4] = res;
        ushort4 pk = {f2bf(res.x), f2bf(res.y), f2bf(res.z), f2bf(res.w)};
        *(ushort4*)&hbf[grow + e * 4] = pk;
    }
}

// ---------------------------------------------------------------------------
extern "C" void kernel_launch(void* const* d_in, const int* in_sizes, int n_in,
                              void* d_out, int out_size, void* d_ws, size_t ws_size,
                              hipStream_t stream) {
    const float* X_obs = (const float*)d_in[0];
    const float* mask  = (const float*)d_in[1];
    const float* W_in  = (const float*)d_in[2];
    const float* b_in  = (const float*)d_in[3];
    const float* gat_W = (const float*)d_in[4];
    const float* gat_a = (const float*)d_in[5];
    const float* ln_g  = (const float*)d_in[6];
    const float* ln_b  = (const float*)d_in[7];
    const float* W_out = (const float*)d_in[8];
    const float* b_out = (const float*)d_in[9];
    float* out = (float*)d_out;

    // Workspace layout:
    //  [0,16M):  Ain bf16 (M x 1024), dead after gemm1; then hwN bf16
    //            [32][1024][64] at [0,4M), ck at [5M,~9.4M), wm at [10M,+256K),
    //            srt at [11M,+128K), sig at [12M,+128K)
    //  [21M,29M): hbuf fp32 (M x 256)
    //  [29M,33M): hbf bf16 (M x 256)
    //  [33M,+):   Wt_in, Wcat, WtO (bf16), slb/srb (fp32), rmaxkey (uint[64])
    char* base = (char*)d_ws;
    unsigned short* Ain = (unsigned short*)base;
    unsigned short* hwN = (unsigned short*)base;
    float* ck   = (float*)(base + (5u << 20));
    float* wm   = (float*)(base + (10u << 20));
    float* srtb = (float*)(base + (11u << 20));
    int*   sig  = (int*)(base + (12u << 20));
    float* hbuf = (float*)(base + (21u << 20));
    unsigned short* hbf   = (unsigned short*)(base + (29u << 20));
    unsigned short* Wt_in = (unsigned short*)(base + (33u << 20));
    unsigned short* Wcat  = Wt_in + (size_t)HID_ * KIN_;        // 256*1024
    unsigned short* WtO   = Wcat + (size_t)NL_ * HID_ * HID_;   // 2*256*256
    float* slb = (float*)(WtO + (size_t)T_ * HID_);             // 32*1024
    float* srb = slb + B_ * NH_ * D_;
    unsigned int* rmaxkey = (unsigned int*)(srb + B_ * NH_ * D_);  // [2][32]

    prep_k<<<2560, 256, 0, stream>>>(X_obs, mask, W_in, gat_W, W_out,
                                     Ain, Wt_in, Wcat, WtO, rmaxkey);

    // h = [X_mean|mask] @ W_in + b_in   (8192x1024)@(1024x256), fp32+bf16 out
    gemm_bf16_k<1><<<dim3(HID_ / 64, M_ / 64), 256, 0, stream>>>(
        Ain, Wt_in, b_in, hbuf, hbf, nullptr, nullptr, nullptr, nullptr,
        HID_, KIN_);

    for (int l = 0; l < NL_; l++) {
        // hW = h @ Wcat[l] -> hwN [bh][m][e] bf16 + fused s_l/s_r/rmax
        gemm_bf16_k<2><<<dim3(HID_ / 64, M_ / 64), 256, 0, stream>>>(
            hbf, Wcat + (size_t)l * HID_ * HID_, nullptr, nullptr, hwN,
            gat_a + (size_t)l * NH_ * 2 * OUT_, slb, srb, rmaxkey + l * 32,
            HID_, HID_);
        // exact rank of sr per bh (counting, whole-GPU parallel)
        rank_k<<<dim3(32, 16), 1024, 0, stream>>>(srb, rmaxkey + l * 32,
                                                  srtb, sig, wm);
        // checkpointed weighted prefix sums over sorted rank
        prefix_k<<<32, 1024, 0, stream>>>(hwN, sig, wm, ck);
        // per-row gather + residual + LayerNorm
        rowln_k<<<256, 512, 0, stream>>>(hbuf, slb, rmaxkey + l * 32,
                                         srtb, sig, wm, ck, hwN,
                                         ln_g + (size_t)l * HID_,
                                         ln_b + (size_t)l * HID_, hbf);
    }

    // out = h @ W_out + b_out  (8192x256)@(256x512), fp32 out
    gemm_bf16_k<0><<<dim3(T_ / 64, M_ / 64), 256, 0, stream>>>(
        hbf, WtO, b_out, out, nullptr, nullptr, nullptr, nullptr, nullptr,
        T_, HID_);
}